// Round 1
// baseline (114.110 us; speedup 1.0000x reference)
//
#include <hip/hip_runtime.h>
#include <math.h>

#define H 2048
#define S 8192
#define JCHUNK 64

// u[k] = sum_j h[j] * W[j*H + k]   (u = W^T h)
// grid: (H/256, H/JCHUNK), block: 256. Coalesced along k.
__global__ void wt_h_kernel(const float* __restrict__ W, const float* __restrict__ h,
                            float* __restrict__ u) {
    int k = blockIdx.x * blockDim.x + threadIdx.x;
    int j0 = blockIdx.y * JCHUNK;
    float acc = 0.f;
#pragma unroll 8
    for (int j = j0; j < j0 + JCHUNK; ++j) {
        acc += h[j] * W[(size_t)j * H + k];
    }
    atomicAdd(&u[k], acc);
}

// e[s] = enc[s] . u   — one wave (64 lanes) per row, 4 waves per block.
__global__ void enc_dot_kernel(const float* __restrict__ enc, const float* __restrict__ u,
                               float* __restrict__ e) {
    int wave = threadIdx.x >> 6;
    int lane = threadIdx.x & 63;
    int s = blockIdx.x * 4 + wave;
    const float4* row = (const float4*)(enc + (size_t)s * H);
    const float4* u4  = (const float4*)u;
    float acc = 0.f;
#pragma unroll
    for (int i = lane; i < H / 4; i += 64) {
        float4 a = row[i];
        float4 b = u4[i];
        acc += a.x * b.x + a.y * b.y + a.z * b.z + a.w * b.w;
    }
#pragma unroll
    for (int off = 32; off > 0; off >>= 1) acc += __shfl_down(acc, off);
    if (lane == 0) e[s] = acc;
}

// softmax over S=8192 values, single block of 1024 threads, 8 vals/thread.
__global__ void softmax_kernel(const float* __restrict__ e, float* __restrict__ out) {
    __shared__ float red[16];
    __shared__ float bcast;
    int tid = threadIdx.x;
    int lane = tid & 63;
    int wv = tid >> 6;

    float vals[8];
    float m = -INFINITY;
#pragma unroll
    for (int i = 0; i < 8; ++i) {
        vals[i] = e[tid + i * 1024];
        m = fmaxf(m, vals[i]);
    }
#pragma unroll
    for (int off = 32; off > 0; off >>= 1) m = fmaxf(m, __shfl_down(m, off));
    if (lane == 0) red[wv] = m;
    __syncthreads();
    if (tid == 0) {
        float mm = red[0];
#pragma unroll
        for (int i = 1; i < 16; ++i) mm = fmaxf(mm, red[i]);
        bcast = mm;
    }
    __syncthreads();
    float M = bcast;

    float ssum = 0.f;
#pragma unroll
    for (int i = 0; i < 8; ++i) {
        vals[i] = __expf(vals[i] - M);
        ssum += vals[i];
    }
#pragma unroll
    for (int off = 32; off > 0; off >>= 1) ssum += __shfl_down(ssum, off);
    if (lane == 0) red[wv] = ssum;
    __syncthreads();
    if (tid == 0) {
        float t = 0.f;
#pragma unroll
        for (int i = 0; i < 16; ++i) t += red[i];
        bcast = t;
    }
    __syncthreads();
    float inv = 1.f / bcast;
#pragma unroll
    for (int i = 0; i < 8; ++i) out[tid + i * 1024] = vals[i] * inv;
}

extern "C" void kernel_launch(void* const* d_in, const int* in_sizes, int n_in,
                              void* d_out, int out_size, void* d_ws, size_t ws_size,
                              hipStream_t stream) {
    const float* hidden = (const float*)d_in[0];  // (1,1,H)
    const float* enc    = (const float*)d_in[1];  // (S,1,H)
    const float* W      = (const float*)d_in[2];  // (H,H)
    // d_in[3] = b, softmax-invariant (adds a constant to all energies) -> ignored.
    float* out = (float*)d_out;                   // (1,1,S)

    float* u = (float*)d_ws;                      // H floats
    float* e = (float*)((char*)d_ws + H * sizeof(float)); // S floats

    hipMemsetAsync(u, 0, H * sizeof(float), stream);

    dim3 g1(H / 256, H / JCHUNK);
    wt_h_kernel<<<g1, 256, 0, stream>>>(W, hidden, u);

    enc_dot_kernel<<<S / 4, 256, 0, stream>>>(enc, u, e);

    softmax_kernel<<<1, 1024, 0, stream>>>(e, out);
}